// Round 8
// baseline (242.658 us; speedup 1.0000x reference)
//
#include <hip/hip_runtime.h>
#include <math.h>

// DP-GCN constants (EPS=1, ALPHA=0.5, DELTA=1):
//   transformed = ((e+1)*x - 1) * (1/(e-1)) + 0.5 = C1*x + C0
#define C1 2.163953413738653f
#define C0 -0.081976706869326f

// NOTE: assumes N <= 65536 so node ids fit u16 (N=50000 here).

static __device__ __forceinline__ unsigned short f2bf(float f) {   // RTN-even
    unsigned b = __float_as_uint(f);
    return (unsigned short)((b + 0x7FFFu + ((b >> 16) & 1u)) >> 16);
}
static __device__ __forceinline__ float bf2f(unsigned short u) {
    return __uint_as_float((unsigned)u << 16);
}

// ---- dual per-block histogram of col>>8 and row>>8 (LDS atomics only) ----
// hist layout: [d*256 + b] cols, [65536 + d*256 + b] rows; gridDim MUST be 256.
__global__ __launch_bounds__(1024) void k_hist2(const int* __restrict__ row,
                                                const int* __restrict__ col, int E, int chunk,
                                                int* __restrict__ hist) {
    __shared__ int hc[256], hr[256];
    int t = threadIdx.x, b = blockIdx.x;
    if (t < 256) { hc[t] = 0; hr[t] = 0; }
    __syncthreads();
    int lo = b * chunk, hi = min(E, lo + chunk);
    for (int i = lo + t; i < hi; i += 1024) {
        atomicAdd(&hc[col[i] >> 8], 1);
        atomicAdd(&hr[row[i] >> 8], 1);
    }
    __syncthreads();
    if (t < 256) {
        hist[t * 256 + b] = hc[t];
        hist[65536 + t * 256 + b] = hr[t];
    }
}

// ---- level-1 exclusive scan over 131072 counts (512 blocks x 256) ----
__global__ void k_scan_a(const int* __restrict__ cnt, int* __restrict__ excl,
                         int* __restrict__ bsum, int n) {
    __shared__ int s[256];
    int idx = blockIdx.x * 256 + threadIdx.x;
    int v = (idx < n) ? cnt[idx] : 0;
    s[threadIdx.x] = v;
    __syncthreads();
    for (int off = 1; off < 256; off <<= 1) {
        int t = (threadIdx.x >= off) ? s[threadIdx.x - off] : 0;
        __syncthreads();
        s[threadIdx.x] += t;
        __syncthreads();
    }
    if (idx < n) excl[idx] = s[threadIdx.x] - v;
    if (threadIdx.x == 255) bsum[blockIdx.x] = s[255];
}

// ---- level-2: each block reduces bsum[0..b-1] and adds to its segment ----
__global__ __launch_bounds__(512) void k_scan_bc(int* __restrict__ excl,
                                                 const int* __restrict__ bsum) {
    __shared__ int s[512];
    int t = threadIdx.x, b = blockIdx.x;
    s[t] = (t < b) ? bsum[t] : 0;
    __syncthreads();
    for (int off = 256; off > 0; off >>= 1) {
        if (t < off) s[t] += s[t + off];
        __syncthreads();
    }
    if (t < 256) excl[b * 256 + t] += s[0];
}

// ---- partition: cbuf[pos]=(col<<16)|row by col>>8; rbuf[pos]=row (u16) by row>>8 ----
__global__ __launch_bounds__(1024) void k_part(const int* __restrict__ row,
                                               const int* __restrict__ col, int E, int chunk,
                                               const int* __restrict__ shist,
                                               unsigned* __restrict__ cbuf,
                                               unsigned short* __restrict__ rbuf) {
    __shared__ int offc[256], offr[256];
    int t = threadIdx.x, b = blockIdx.x;
    if (t < 256) {
        offc[t] = shist[t * 256 + b];
        offr[t] = shist[65536 + t * 256 + b] - E;
    }
    __syncthreads();
    int lo = b * chunk, hi = min(E, lo + chunk);
    for (int i = lo + t; i < hi; i += 1024) {
        int r = row[i], c = col[i];
        int pc = atomicAdd(&offc[c >> 8], 1);
        cbuf[pc] = ((unsigned)c << 16) | (unsigned)r;
        int pr = atomicAdd(&offr[r >> 8], 1);
        rbuf[pr] = (unsigned short)r;
    }
}

// ---- per row-bucket: exact out-degree -> dis -> bf16 xt rows (fused) ----
__global__ __launch_bounds__(256) void k_deg2xt(const unsigned short* __restrict__ rbuf,
                                                const int* __restrict__ shist,
                                                const int* __restrict__ priv,
                                                const float* __restrict__ x, int N, int E,
                                                float* __restrict__ dis,
                                                unsigned short* __restrict__ xt) {
    __shared__ int cnt[256];
    __shared__ float sdis[256];
    __shared__ int spriv[256];
    int t = threadIdx.x, b = blockIdx.x;
    cnt[t] = 0;
    __syncthreads();
    int rs = shist[65536 + b * 256] - E;
    int re = shist[65536 + (b + 1) * 256] - E;   // b < 255 always (N/256 buckets)
    for (int i = rs + t; i < re; i += 256) atomicAdd(&cnt[rbuf[i] & 255], 1);
    __syncthreads();
    int node = b * 256 + t;
    float dv = rsqrtf((float)(cnt[t] + 1));       // +1 self loop
    if (node < N) {
        dis[node] = dv;
        sdis[t] = dv;
        spriv[t] = priv[node];
    } else { sdis[t] = 0.f; spriv[t] = 0; }
    __syncthreads();
    int base = b * 256;
    for (int i = t; i < 256 * 16; i += 256) {     // 16 float4 per node
        int ln = i >> 4;
        int n2 = base + ln;
        if (n2 >= N) continue;
        float d2 = sdis[ln];
        int p = spriv[ln];
        float4 v = ((const float4*)x)[(size_t)n2 * 16 + (i & 15)];
        float4 tr;
        tr.x = p ? fmaf(C1, v.x, C0) : v.x;
        tr.y = p ? fmaf(C1, v.y, C0) : v.y;
        tr.z = p ? fmaf(C1, v.z, C0) : v.z;
        tr.w = p ? fmaf(C1, v.w, C0) : v.w;
        ushort4 o;
        o.x = f2bf(d2 * tr.x); o.y = f2bf(d2 * tr.y);
        o.z = f2bf(d2 * tr.z); o.w = f2bf(d2 * tr.w);
        ((ushort4*)xt)[(size_t)n2 * 16 + (i & 15)] = o;
    }
}

// ---- per col-bucket: cntC/colStart + eSrc[pos] = row (u16) ----
__global__ __launch_bounds__(256) void k_csr(const unsigned* __restrict__ cbuf,
                                             const int* __restrict__ shist, int N, int E,
                                             int* __restrict__ cntC, int* __restrict__ colStart,
                                             unsigned short* __restrict__ eSrc) {
    __shared__ int cnt[256], ls[256], cnt2[256];
    int t = threadIdx.x, b = blockIdx.x;
    cnt[t] = 0; cnt2[t] = 0;
    __syncthreads();
    int cs = shist[b * 256];
    int ce = shist[(b + 1) * 256];                // b < 255 always
    for (int i = cs + t; i < ce; i += 256) atomicAdd(&cnt[(cbuf[i] >> 16) & 255], 1);
    __syncthreads();
    int v = cnt[t];
    ls[t] = v;
    __syncthreads();
    for (int off = 1; off < 256; off <<= 1) {
        int u = (t >= off) ? ls[t - off] : 0;
        __syncthreads();
        ls[t] += u;
        __syncthreads();
    }
    int excl = ls[t] - v;
    int c = b * 256 + t;
    if (c < N) { cntC[c] = v; colStart[c] = cs + excl; }
    __syncthreads();
    ls[t] = excl;
    __syncthreads();
    for (int i = cs + t; i < ce; i += 256) {
        unsigned e = cbuf[i];
        int d = (e >> 16) & 255;
        int pos = cs + ls[d] + atomicAdd(&cnt2[d], 1);
        eSrc[pos] = (unsigned short)(e & 0xFFFFu);
    }
}

// ---- fused conv1-gather + MLP: one 64-node tile per block ----
// phase 1: 4 waves gather 16 nodes each, writing As[k][m] (=agg1) straight to LDS
// phase 2: hps = bf16( dis * (relu(A @ W1 + b1) @ W2) )
__global__ __launch_bounds__(256) void k_gather1_mlp(const unsigned short* __restrict__ xt,
                                                     const unsigned short* __restrict__ eSrc,
                                                     const int* __restrict__ colStart,
                                                     const int* __restrict__ cntC,
                                                     const float* __restrict__ dis,
                                                     const float* __restrict__ W1,
                                                     const float* __restrict__ b1,
                                                     const float* __restrict__ W2,
                                                     unsigned short* __restrict__ hps, int N) {
    __shared__ float hidT[128 * 68];        // 34816 B; As = rows 0..63
    __shared__ float W2s[128 * 32];         // 16 KB
    float* As = hidT;
    const int t = threadIdx.x;
    const int base = blockIdx.x * 64;

    for (int i = t * 4; i < 128 * 32; i += 1024)
        *(float4*)&W2s[i] = *(const float4*)&W2[i];

    // ---- phase 1: gather 64 node rows into As[k][m] ----
    {
        int wave = t >> 6, lane = t & 63;
        for (int q = 0; q < 16; ++q) {
            int m = wave * 16 + q;
            int c = base + m;
            if (c >= N) c = N - 1;              // clamp; result unused
            float s = bf2f(xt[(size_t)c * 64 + lane]);   // self loop
            int start = colStart[c], cnt = cntC[c];
            for (int bb = 0; bb < cnt; bb += 64) {
                int mm = min(cnt - bb, 64);
                int ids = (lane < mm) ? (int)eSrc[start + bb + lane] : 0;
                int k = 0;
                for (; k + 4 <= mm; k += 4) {
                    int r0 = __shfl(ids, k),     r1 = __shfl(ids, k + 1);
                    int r2 = __shfl(ids, k + 2), r3 = __shfl(ids, k + 3);
                    float x0 = bf2f(xt[(size_t)r0 * 64 + lane]);
                    float x1 = bf2f(xt[(size_t)r1 * 64 + lane]);
                    float x2 = bf2f(xt[(size_t)r2 * 64 + lane]);
                    float x3 = bf2f(xt[(size_t)r3 * 64 + lane]);
                    s += x0; s += x1; s += x2; s += x3;
                }
                for (; k < mm; ++k) {
                    int r = __shfl(ids, k);
                    s += bf2f(xt[(size_t)r * 64 + lane]);
                }
            }
            As[lane * 68 + m] = dis[c] * s;
        }
    }
    __syncthreads();

    // ---- phase 2a: layer 1, out tile 64m x 128n, thread = 8m x 4n ----
    const int tn = t & 31;
    const int tm = t >> 5;
    float4 bv = *(const float4*)&b1[tn * 4];
    float acc[8][4];
    #pragma unroll
    for (int i = 0; i < 8; ++i) {
        acc[i][0] = bv.x; acc[i][1] = bv.y; acc[i][2] = bv.z; acc[i][3] = bv.w;
    }
    #pragma unroll 4
    for (int k = 0; k < 64; ++k) {
        float4 w  = *(const float4*)&W1[k * 128 + tn * 4];
        float4 a0 = *(const float4*)&As[k * 68 + tm * 8];
        float4 a1 = *(const float4*)&As[k * 68 + tm * 8 + 4];
        const float av[8] = {a0.x, a0.y, a0.z, a0.w, a1.x, a1.y, a1.z, a1.w};
        #pragma unroll
        for (int i = 0; i < 8; ++i) {
            acc[i][0] = fmaf(av[i], w.x, acc[i][0]);
            acc[i][1] = fmaf(av[i], w.y, acc[i][1]);
            acc[i][2] = fmaf(av[i], w.z, acc[i][2]);
            acc[i][3] = fmaf(av[i], w.w, acc[i][3]);
        }
    }
    __syncthreads();

    #pragma unroll
    for (int j = 0; j < 4; ++j)
        #pragma unroll
        for (int i = 0; i < 8; ++i)
            hidT[(tn * 4 + j) * 68 + tm * 8 + i] = fmaxf(acc[i][j], 0.f);
    __syncthreads();

    // ---- phase 2b: layer 2, out tile 64m x 32o, thread = 4m x 2o ----
    const int to  = t & 15;
    const int tm2 = t >> 4;
    float o0[4] = {0.f, 0.f, 0.f, 0.f};
    float o1[4] = {0.f, 0.f, 0.f, 0.f};
    #pragma unroll 4
    for (int kh = 0; kh < 128; ++kh) {
        float4 a = *(const float4*)&hidT[kh * 68 + tm2 * 4];
        float2 w = *(const float2*)&W2s[kh * 32 + to * 2];
        const float av[4] = {a.x, a.y, a.z, a.w};
        #pragma unroll
        for (int i = 0; i < 4; ++i) {
            o0[i] = fmaf(av[i], w.x, o0[i]);
            o1[i] = fmaf(av[i], w.y, o1[i]);
        }
    }
    #pragma unroll
    for (int i = 0; i < 4; ++i) {
        int node = base + tm2 * 4 + i;
        if (node < N) {
            float dv = dis[node];
            ushort2 o = make_ushort2(f2bf(o0[i] * dv), f2bf(o1[i] * dv));
            *(ushort2*)&hps[(size_t)node * 32 + to * 2] = o;
        }
    }
}

// conv2 by gather: out[c] = b2 - dis_c * (hps_c + sum_r hps_r); 32 lanes per c
__global__ __launch_bounds__(256) void k_gather2(const unsigned short* __restrict__ hps,
                                                 const unsigned short* __restrict__ eSrc,
                                                 const int* __restrict__ colStart,
                                                 const int* __restrict__ cntC,
                                                 const float* __restrict__ dis,
                                                 const float* __restrict__ b2,
                                                 float* __restrict__ out, int N) {
    int t = blockIdx.x * blockDim.x + threadIdx.x;
    int c = t >> 5, j = t & 31;
    if (c >= N) return;
    float s = bf2f(hps[(size_t)c * 32 + j]);   // self loop
    int start = colStart[c], cnt = cntC[c];
    for (int base = 0; base < cnt; base += 32) {
        int m = min(cnt - base, 32);
        int ids = (j < m) ? (int)eSrc[start + base + j] : 0;
        int k = 0;
        for (; k + 4 <= m; k += 4) {
            int r0 = __shfl(ids, k, 32),     r1 = __shfl(ids, k + 1, 32);
            int r2 = __shfl(ids, k + 2, 32), r3 = __shfl(ids, k + 3, 32);
            float h0 = bf2f(hps[(size_t)r0 * 32 + j]);
            float h1 = bf2f(hps[(size_t)r1 * 32 + j]);
            float h2 = bf2f(hps[(size_t)r2 * 32 + j]);
            float h3 = bf2f(hps[(size_t)r3 * 32 + j]);
            s += h0; s += h1; s += h2; s += h3;
        }
        for (; k < m; ++k) {
            int r = __shfl(ids, k, 32);
            s += bf2f(hps[(size_t)r * 32 + j]);
        }
    }
    out[(size_t)c * 32 + j] = b2[j] - dis[c] * s;
}

extern "C" void kernel_launch(void* const* d_in, const int* in_sizes, int n_in,
                              void* d_out, int out_size, void* d_ws, size_t ws_size,
                              hipStream_t stream) {
    const float* x    = (const float*)d_in[0];
    const int*   ei   = (const int*)d_in[1];
    const int*   priv = (const int*)d_in[2];
    const float* W1   = (const float*)d_in[3];
    const float* b1   = (const float*)d_in[4];
    const float* W2   = (const float*)d_in[5];
    const float* b2   = (const float*)d_in[6];
    float* out = (float*)d_out;

    const int N = in_sizes[2];
    const int E = in_sizes[1] / 2;
    const int* row = ei;
    const int* col = ei + E;

    char* ws = (char*)d_ws;
    size_t off = 0;
    auto take = [&](size_t bytes) { char* p = ws + off; off = (off + bytes + 255) & ~(size_t)255; return p; };
    int*            hist     = (int*)           take((size_t)131072 * 4);
    int*            shist    = (int*)           take((size_t)131072 * 4);
    int*            bsum     = (int*)           take(512 * 4);
    unsigned*       cbuf     = (unsigned*)      take((size_t)E * 4);
    unsigned short* rbuf     = (unsigned short*)take((size_t)E * 2);
    float*          dis      = (float*)         take((size_t)N * 4);
    int*            cntC     = (int*)           take((size_t)N * 4);
    int*            colStart = (int*)           take((size_t)N * 4);
    unsigned short* eSrc     = (unsigned short*)take((size_t)E * 2);
    unsigned short* xt       = (unsigned short*)take((size_t)N * 64 * 2);
    unsigned short* hps      = (unsigned short*)take((size_t)N * 32 * 2);
    (void)ws_size;

    const int chunk = (E + 255) / 256;
    const int nbk = (N + 255) / 256;     // node buckets (196 < 255)

    k_hist2      <<<256, 1024, 0, stream>>>(row, col, E, chunk, hist);
    k_scan_a     <<<512, 256, 0, stream>>>(hist, shist, bsum, 131072);
    k_scan_bc    <<<512, 512, 0, stream>>>(shist, bsum);
    k_part       <<<256, 1024, 0, stream>>>(row, col, E, chunk, shist, cbuf, rbuf);
    k_deg2xt     <<<nbk, 256, 0, stream>>>(rbuf, shist, priv, x, N, E, dis, xt);
    k_csr        <<<nbk, 256, 0, stream>>>(cbuf, shist, N, E, cntC, colStart, eSrc);
    k_gather1_mlp<<<(N + 63) / 64, 256, 0, stream>>>(xt, eSrc, colStart, cntC, dis, W1, b1, W2, hps, N);
    k_gather2    <<<((size_t)N * 32 + 255) / 256, 256, 0, stream>>>(hps, eSrc, colStart, cntC, dis, b2, out, N);
}

// Round 9
// 175.765 us; speedup vs baseline: 1.3806x; 1.3806x over previous
//
#include <hip/hip_runtime.h>
#include <math.h>

// DP-GCN constants (EPS=1, ALPHA=0.5, DELTA=1):
//   transformed = ((e+1)*x - 1) * (1/(e-1)) + 0.5 = C1*x + C0
#define C1 2.163953413738653f
#define C0 -0.081976706869326f

// NOTE: assumes N <= 65536 so node ids fit u16 (N=50000 here).

static __device__ __forceinline__ unsigned short f2bf(float f) {   // RTN-even
    unsigned b = __float_as_uint(f);
    return (unsigned short)((b + 0x7FFFu + ((b >> 16) & 1u)) >> 16);
}
static __device__ __forceinline__ float bf2f(unsigned short u) {
    return __uint_as_float((unsigned)u << 16);
}

// ---- dual per-block histogram of col>>8 and row>>8 (LDS atomics only) ----
// hist layout: [d*256 + b] cols, [65536 + d*256 + b] rows; gridDim MUST be 256.
__global__ __launch_bounds__(1024) void k_hist2(const int* __restrict__ row,
                                                const int* __restrict__ col, int E, int chunk,
                                                int* __restrict__ hist) {
    __shared__ int hc[256], hr[256];
    int t = threadIdx.x, b = blockIdx.x;
    if (t < 256) { hc[t] = 0; hr[t] = 0; }
    __syncthreads();
    int lo = b * chunk, hi = min(E, lo + chunk);
    for (int i = lo + t; i < hi; i += 1024) {
        atomicAdd(&hc[col[i] >> 8], 1);
        atomicAdd(&hr[row[i] >> 8], 1);
    }
    __syncthreads();
    if (t < 256) {
        hist[t * 256 + b] = hc[t];
        hist[65536 + t * 256 + b] = hr[t];
    }
}

// ---- level-1 exclusive scan over 131072 counts (512 blocks x 256) ----
__global__ void k_scan_a(const int* __restrict__ cnt, int* __restrict__ excl,
                         int* __restrict__ bsum, int n) {
    __shared__ int s[256];
    int idx = blockIdx.x * 256 + threadIdx.x;
    int v = (idx < n) ? cnt[idx] : 0;
    s[threadIdx.x] = v;
    __syncthreads();
    for (int off = 1; off < 256; off <<= 1) {
        int t = (threadIdx.x >= off) ? s[threadIdx.x - off] : 0;
        __syncthreads();
        s[threadIdx.x] += t;
        __syncthreads();
    }
    if (idx < n) excl[idx] = s[threadIdx.x] - v;
    if (threadIdx.x == 255) bsum[blockIdx.x] = s[255];
}

// ---- level-2: each block reduces bsum[0..b-1] and adds to its segment ----
__global__ __launch_bounds__(512) void k_scan_bc(int* __restrict__ excl,
                                                 const int* __restrict__ bsum) {
    __shared__ int s[512];
    int t = threadIdx.x, b = blockIdx.x;
    s[t] = (t < b) ? bsum[t] : 0;
    __syncthreads();
    for (int off = 256; off > 0; off >>= 1) {
        if (t < off) s[t] += s[t + off];
        __syncthreads();
    }
    if (t < 256) excl[b * 256 + t] += s[0];
}

// ---- partition: cbuf[pos]=(col<<16)|row by col>>8; rbuf[pos]=row (u16) by row>>8 ----
__global__ __launch_bounds__(1024) void k_part(const int* __restrict__ row,
                                               const int* __restrict__ col, int E, int chunk,
                                               const int* __restrict__ shist,
                                               unsigned* __restrict__ cbuf,
                                               unsigned short* __restrict__ rbuf) {
    __shared__ int offc[256], offr[256];
    int t = threadIdx.x, b = blockIdx.x;
    if (t < 256) {
        offc[t] = shist[t * 256 + b];
        offr[t] = shist[65536 + t * 256 + b] - E;
    }
    __syncthreads();
    int lo = b * chunk, hi = min(E, lo + chunk);
    for (int i = lo + t; i < hi; i += 1024) {
        int r = row[i], c = col[i];
        int pc = atomicAdd(&offc[c >> 8], 1);
        cbuf[pc] = ((unsigned)c << 16) | (unsigned)r;
        int pr = atomicAdd(&offr[r >> 8], 1);
        rbuf[pr] = (unsigned short)r;
    }
}

// ---- merged per-bucket build: blocks [0,nbk) do deg->dis->xt; [nbk,2nbk) do CSR ----
__global__ __launch_bounds__(256) void k_build(const unsigned short* __restrict__ rbuf,
                                               const unsigned* __restrict__ cbuf,
                                               const int* __restrict__ shist,
                                               const int* __restrict__ priv,
                                               const float* __restrict__ x, int N, int E, int nbk,
                                               float* __restrict__ dis,
                                               unsigned short* __restrict__ xt,
                                               int* __restrict__ cntC, int* __restrict__ colStart,
                                               unsigned short* __restrict__ eSrc) {
    __shared__ int s1[256], s2[256], s3[256];
    int t = threadIdx.x;
    if ((int)blockIdx.x < nbk) {
        // ---- deg -> dis -> bf16 xt ----
        int b = blockIdx.x;
        s1[t] = 0;
        __syncthreads();
        int rs = shist[65536 + b * 256] - E;
        int re = shist[65536 + (b + 1) * 256] - E;   // b+1 <= nbk <= 255
        for (int i = rs + t; i < re; i += 256) atomicAdd(&s1[rbuf[i] & 255], 1);
        __syncthreads();
        int node = b * 256 + t;
        float dv = rsqrtf((float)(s1[t] + 1));       // +1 self loop
        if (node < N) {
            dis[node] = dv;
            s2[t] = __float_as_int(dv);
            s3[t] = priv[node];
        } else { s2[t] = 0; s3[t] = 0; }
        __syncthreads();
        int base = b * 256;
        for (int i = t; i < 256 * 16; i += 256) {     // 16 float4 per node
            int ln = i >> 4;
            int n2 = base + ln;
            if (n2 >= N) continue;
            float d2 = __int_as_float(s2[ln]);
            int p = s3[ln];
            float4 v = ((const float4*)x)[(size_t)n2 * 16 + (i & 15)];
            float4 tr;
            tr.x = p ? fmaf(C1, v.x, C0) : v.x;
            tr.y = p ? fmaf(C1, v.y, C0) : v.y;
            tr.z = p ? fmaf(C1, v.z, C0) : v.z;
            tr.w = p ? fmaf(C1, v.w, C0) : v.w;
            ushort4 o;
            o.x = f2bf(d2 * tr.x); o.y = f2bf(d2 * tr.y);
            o.z = f2bf(d2 * tr.z); o.w = f2bf(d2 * tr.w);
            ((ushort4*)xt)[(size_t)n2 * 16 + (i & 15)] = o;
        }
    } else {
        // ---- CSR: cntC/colStart + eSrc[pos] = row (u16) ----
        int b = blockIdx.x - nbk;
        s1[t] = 0; s3[t] = 0;
        __syncthreads();
        int cs = shist[b * 256];
        int ce = shist[(b + 1) * 256];
        for (int i = cs + t; i < ce; i += 256) atomicAdd(&s1[(cbuf[i] >> 16) & 255], 1);
        __syncthreads();
        int v = s1[t];
        s2[t] = v;
        __syncthreads();
        for (int off = 1; off < 256; off <<= 1) {
            int u = (t >= off) ? s2[t - off] : 0;
            __syncthreads();
            s2[t] += u;
            __syncthreads();
        }
        int excl = s2[t] - v;
        int c = b * 256 + t;
        if (c < N) { cntC[c] = v; colStart[c] = cs + excl; }
        __syncthreads();
        s2[t] = excl;
        __syncthreads();
        for (int i = cs + t; i < ce; i += 256) {
            unsigned e = cbuf[i];
            int d = (e >> 16) & 255;
            int pos = cs + s2[d] + atomicAdd(&s3[d], 1);
            eSrc[pos] = (unsigned short)(e & 0xFFFFu);
        }
    }
}

// conv1 by gather: agg1b[c] = bf16( dis_c * (xt_c + sum_r xt_r) ); wave per c, 8x unroll
__global__ __launch_bounds__(256) void k_gather1(const unsigned short* __restrict__ xt,
                                                 const unsigned short* __restrict__ eSrc,
                                                 const int* __restrict__ colStart,
                                                 const int* __restrict__ cntC,
                                                 const float* __restrict__ dis,
                                                 unsigned short* __restrict__ agg1b, int N) {
    int t = blockIdx.x * blockDim.x + threadIdx.x;
    int c = t >> 6, d = t & 63;
    if (c >= N) return;
    float s = bf2f(xt[(size_t)c * 64 + d]);   // self loop term
    int start = colStart[c], cnt = cntC[c];
    for (int base = 0; base < cnt; base += 64) {
        int m = min(cnt - base, 64);
        int ids = (d < m) ? (int)eSrc[start + base + d] : 0;
        int k = 0;
        for (; k + 8 <= m; k += 8) {
            int r0 = __shfl(ids, k),     r1 = __shfl(ids, k + 1);
            int r2 = __shfl(ids, k + 2), r3 = __shfl(ids, k + 3);
            int r4 = __shfl(ids, k + 4), r5 = __shfl(ids, k + 5);
            int r6 = __shfl(ids, k + 6), r7 = __shfl(ids, k + 7);
            float x0 = bf2f(xt[(size_t)r0 * 64 + d]);
            float x1 = bf2f(xt[(size_t)r1 * 64 + d]);
            float x2 = bf2f(xt[(size_t)r2 * 64 + d]);
            float x3 = bf2f(xt[(size_t)r3 * 64 + d]);
            float x4 = bf2f(xt[(size_t)r4 * 64 + d]);
            float x5 = bf2f(xt[(size_t)r5 * 64 + d]);
            float x6 = bf2f(xt[(size_t)r6 * 64 + d]);
            float x7 = bf2f(xt[(size_t)r7 * 64 + d]);
            s += x0; s += x1; s += x2; s += x3;
            s += x4; s += x5; s += x6; s += x7;
        }
        for (; k + 4 <= m; k += 4) {
            int r0 = __shfl(ids, k),     r1 = __shfl(ids, k + 1);
            int r2 = __shfl(ids, k + 2), r3 = __shfl(ids, k + 3);
            float x0 = bf2f(xt[(size_t)r0 * 64 + d]);
            float x1 = bf2f(xt[(size_t)r1 * 64 + d]);
            float x2 = bf2f(xt[(size_t)r2 * 64 + d]);
            float x3 = bf2f(xt[(size_t)r3 * 64 + d]);
            s += x0; s += x1; s += x2; s += x3;
        }
        for (; k < m; ++k) {
            int r = __shfl(ids, k);
            s += bf2f(xt[(size_t)r * 64 + d]);
        }
    }
    agg1b[(size_t)c * 64 + d] = f2bf(dis[c] * s);
}

// fused MLP: hps = bf16( dis * (relu(agg1 @ W1 + b1) @ W2) ); one 64-node tile/block
__global__ __launch_bounds__(256) void k_mlp_fused(const unsigned short* __restrict__ agg1b,
                                                   const float* __restrict__ W1,
                                                   const float* __restrict__ b1,
                                                   const float* __restrict__ W2,
                                                   const float* __restrict__ dis,
                                                   unsigned short* __restrict__ hps, int N) {
    __shared__ float hidT[128 * 68];        // 34816 B; As = rows 0..63
    __shared__ float W2s[128 * 32];         // 16 KB
    float* As = hidT;
    const int t = threadIdx.x;
    const int base = blockIdx.x * 64;

    for (int i = t * 4; i < 128 * 32; i += 1024)
        *(float4*)&W2s[i] = *(const float4*)&W2[i];

    {
        int kq = t & 15, mm = t >> 4;       // kq: quad of 4 dims
        #pragma unroll
        for (int p = 0; p < 4; ++p) {
            int m = mm + p * 16;
            int node = base + m;
            if (node >= N) node = N - 1;    // clamp; result unused
            ushort4 v = ((const ushort4*)agg1b)[(size_t)node * 16 + kq];
            As[(kq * 4 + 0) * 68 + m] = bf2f(v.x);
            As[(kq * 4 + 1) * 68 + m] = bf2f(v.y);
            As[(kq * 4 + 2) * 68 + m] = bf2f(v.z);
            As[(kq * 4 + 3) * 68 + m] = bf2f(v.w);
        }
    }
    __syncthreads();

    const int tn = t & 31;
    const int tm = t >> 5;
    float4 bv = *(const float4*)&b1[tn * 4];
    float acc[8][4];
    #pragma unroll
    for (int i = 0; i < 8; ++i) {
        acc[i][0] = bv.x; acc[i][1] = bv.y; acc[i][2] = bv.z; acc[i][3] = bv.w;
    }
    #pragma unroll 4
    for (int k = 0; k < 64; ++k) {
        float4 w  = *(const float4*)&W1[k * 128 + tn * 4];
        float4 a0 = *(const float4*)&As[k * 68 + tm * 8];
        float4 a1 = *(const float4*)&As[k * 68 + tm * 8 + 4];
        const float av[8] = {a0.x, a0.y, a0.z, a0.w, a1.x, a1.y, a1.z, a1.w};
        #pragma unroll
        for (int i = 0; i < 8; ++i) {
            acc[i][0] = fmaf(av[i], w.x, acc[i][0]);
            acc[i][1] = fmaf(av[i], w.y, acc[i][1]);
            acc[i][2] = fmaf(av[i], w.z, acc[i][2]);
            acc[i][3] = fmaf(av[i], w.w, acc[i][3]);
        }
    }
    __syncthreads();

    #pragma unroll
    for (int j = 0; j < 4; ++j)
        #pragma unroll
        for (int i = 0; i < 8; ++i)
            hidT[(tn * 4 + j) * 68 + tm * 8 + i] = fmaxf(acc[i][j], 0.f);
    __syncthreads();

    const int to  = t & 15;
    const int tm2 = t >> 4;
    float o0[4] = {0.f, 0.f, 0.f, 0.f};
    float o1[4] = {0.f, 0.f, 0.f, 0.f};
    #pragma unroll 4
    for (int kh = 0; kh < 128; ++kh) {
        float4 a = *(const float4*)&hidT[kh * 68 + tm2 * 4];
        float2 w = *(const float2*)&W2s[kh * 32 + to * 2];
        const float av[4] = {a.x, a.y, a.z, a.w};
        #pragma unroll
        for (int i = 0; i < 4; ++i) {
            o0[i] = fmaf(av[i], w.x, o0[i]);
            o1[i] = fmaf(av[i], w.y, o1[i]);
        }
    }
    #pragma unroll
    for (int i = 0; i < 4; ++i) {
        int node = base + tm2 * 4 + i;
        if (node < N) {
            float dv = dis[node];
            ushort2 o = make_ushort2(f2bf(o0[i] * dv), f2bf(o1[i] * dv));
            *(ushort2*)&hps[(size_t)node * 32 + to * 2] = o;
        }
    }
}

// conv2 by gather: out[c] = b2 - dis_c * (hps_c + sum_r hps_r); 32 lanes per c, 8x unroll
__global__ __launch_bounds__(256) void k_gather2(const unsigned short* __restrict__ hps,
                                                 const unsigned short* __restrict__ eSrc,
                                                 const int* __restrict__ colStart,
                                                 const int* __restrict__ cntC,
                                                 const float* __restrict__ dis,
                                                 const float* __restrict__ b2,
                                                 float* __restrict__ out, int N) {
    int t = blockIdx.x * blockDim.x + threadIdx.x;
    int c = t >> 5, j = t & 31;
    if (c >= N) return;
    float s = bf2f(hps[(size_t)c * 32 + j]);   // self loop
    int start = colStart[c], cnt = cntC[c];
    for (int base = 0; base < cnt; base += 32) {
        int m = min(cnt - base, 32);
        int ids = (j < m) ? (int)eSrc[start + base + j] : 0;
        int k = 0;
        for (; k + 8 <= m; k += 8) {
            int r0 = __shfl(ids, k, 32),     r1 = __shfl(ids, k + 1, 32);
            int r2 = __shfl(ids, k + 2, 32), r3 = __shfl(ids, k + 3, 32);
            int r4 = __shfl(ids, k + 4, 32), r5 = __shfl(ids, k + 5, 32);
            int r6 = __shfl(ids, k + 6, 32), r7 = __shfl(ids, k + 7, 32);
            float h0 = bf2f(hps[(size_t)r0 * 32 + j]);
            float h1 = bf2f(hps[(size_t)r1 * 32 + j]);
            float h2 = bf2f(hps[(size_t)r2 * 32 + j]);
            float h3 = bf2f(hps[(size_t)r3 * 32 + j]);
            float h4 = bf2f(hps[(size_t)r4 * 32 + j]);
            float h5 = bf2f(hps[(size_t)r5 * 32 + j]);
            float h6 = bf2f(hps[(size_t)r6 * 32 + j]);
            float h7 = bf2f(hps[(size_t)r7 * 32 + j]);
            s += h0; s += h1; s += h2; s += h3;
            s += h4; s += h5; s += h6; s += h7;
        }
        for (; k + 4 <= m; k += 4) {
            int r0 = __shfl(ids, k, 32),     r1 = __shfl(ids, k + 1, 32);
            int r2 = __shfl(ids, k + 2, 32), r3 = __shfl(ids, k + 3, 32);
            float h0 = bf2f(hps[(size_t)r0 * 32 + j]);
            float h1 = bf2f(hps[(size_t)r1 * 32 + j]);
            float h2 = bf2f(hps[(size_t)r2 * 32 + j]);
            float h3 = bf2f(hps[(size_t)r3 * 32 + j]);
            s += h0; s += h1; s += h2; s += h3;
        }
        for (; k < m; ++k) {
            int r = __shfl(ids, k, 32);
            s += bf2f(hps[(size_t)r * 32 + j]);
        }
    }
    out[(size_t)c * 32 + j] = b2[j] - dis[c] * s;
}

extern "C" void kernel_launch(void* const* d_in, const int* in_sizes, int n_in,
                              void* d_out, int out_size, void* d_ws, size_t ws_size,
                              hipStream_t stream) {
    const float* x    = (const float*)d_in[0];
    const int*   ei   = (const int*)d_in[1];
    const int*   priv = (const int*)d_in[2];
    const float* W1   = (const float*)d_in[3];
    const float* b1   = (const float*)d_in[4];
    const float* W2   = (const float*)d_in[5];
    const float* b2   = (const float*)d_in[6];
    float* out = (float*)d_out;

    const int N = in_sizes[2];
    const int E = in_sizes[1] / 2;
    const int* row = ei;
    const int* col = ei + E;

    char* ws = (char*)d_ws;
    size_t off = 0;
    auto take = [&](size_t bytes) { char* p = ws + off; off = (off + bytes + 255) & ~(size_t)255; return p; };
    int*            hist     = (int*)           take((size_t)131072 * 4);
    int*            shist    = (int*)           take((size_t)131072 * 4);
    int*            bsum     = (int*)           take(512 * 4);
    unsigned*       cbuf     = (unsigned*)      take((size_t)E * 4);
    unsigned short* rbuf     = (unsigned short*)take((size_t)E * 2);
    float*          dis      = (float*)         take((size_t)N * 4);
    int*            cntC     = (int*)           take((size_t)N * 4);
    int*            colStart = (int*)           take((size_t)N * 4);
    unsigned short* eSrc     = (unsigned short*)take((size_t)E * 2);
    unsigned short* xt       = (unsigned short*)take((size_t)N * 64 * 2);
    unsigned short* agg1b    = (unsigned short*)take((size_t)N * 64 * 2);
    unsigned short* hps      = (unsigned short*)take((size_t)N * 32 * 2);
    (void)ws_size;

    const int chunk = (E + 255) / 256;
    const int nbk = (N + 255) / 256;     // node buckets (196 < 255)

    k_hist2    <<<256, 1024, 0, stream>>>(row, col, E, chunk, hist);
    k_scan_a   <<<512, 256, 0, stream>>>(hist, shist, bsum, 131072);
    k_scan_bc  <<<512, 512, 0, stream>>>(shist, bsum);
    k_part     <<<256, 1024, 0, stream>>>(row, col, E, chunk, shist, cbuf, rbuf);
    k_build    <<<2 * nbk, 256, 0, stream>>>(rbuf, cbuf, shist, priv, x, N, E, nbk,
                                             dis, xt, cntC, colStart, eSrc);
    k_gather1  <<<((size_t)N * 64 + 255) / 256, 256, 0, stream>>>(xt, eSrc, colStart, cntC, dis, agg1b, N);
    k_mlp_fused<<<(N + 63) / 64, 256, 0, stream>>>(agg1b, W1, b1, W2, dis, hps, N);
    k_gather2  <<<((size_t)N * 32 + 255) / 256, 256, 0, stream>>>(hps, eSrc, colStart, cntC, dis, b2, out, N);
}

// Round 10
// 157.916 us; speedup vs baseline: 1.5366x; 1.1130x over previous
//
#include <hip/hip_runtime.h>
#include <math.h>

// DP-GCN constants (EPS=1, ALPHA=0.5, DELTA=1):
//   transformed = ((e+1)*x - 1) * (1/(e-1)) + 0.5 = C1*x + C0
#define C1 2.163953413738653f
#define C0 -0.081976706869326f

// NOTE: assumes N <= 65536 so node ids fit u16 (N=50000 here).

typedef __attribute__((ext_vector_type(8))) short bf16x8;
typedef __attribute__((ext_vector_type(4))) float f32x4;

static __device__ __forceinline__ unsigned short f2bf(float f) {   // RTN-even
    unsigned b = __float_as_uint(f);
    return (unsigned short)((b + 0x7FFFu + ((b >> 16) & 1u)) >> 16);
}
static __device__ __forceinline__ float bf2f(unsigned short u) {
    return __uint_as_float((unsigned)u << 16);
}

// ---- dual per-block histogram of col>>8 / row>>8; blocks 0/1 also convert W1/W2
// to bf16 swizzled into MFMA B-fragment order. hist[d*256+b] cols, [65536+d*256+b] rows.
__global__ __launch_bounds__(1024) void k_hist2(const int* __restrict__ row,
                                                const int* __restrict__ col, int E, int chunk,
                                                int* __restrict__ hist,
                                                const float* __restrict__ W1,
                                                const float* __restrict__ W2,
                                                unsigned short* __restrict__ W1b,
                                                unsigned short* __restrict__ W2b) {
    __shared__ int hc[256], hr[256];
    int t = threadIdx.x, b = blockIdx.x;
    if (t < 256) { hc[t] = 0; hr[t] = 0; }
    __syncthreads();
    int lo = b * chunk, hi = min(E, lo + chunk);
    for (int i = lo + t; i < hi; i += 1024) {
        atomicAdd(&hc[col[i] >> 8], 1);
        atomicAdd(&hr[row[i] >> 8], 1);
    }
    __syncthreads();
    if (t < 256) {
        hist[t * 256 + b] = hc[t];
        hist[65536 + t * 256 + b] = hr[t];
    }
    // B-fragment swizzle: frag element j of lane l for (ntile, ktile) holds
    // B[k = kt*32 + (l>>4)*8 + j][n = nt*16 + (l&15)], stored contiguously.
    if (b == 0) {
        for (int i = t; i < 8192; i += 1024) {           // W1: 8 nt x 2 kt
            int j = i & 7, l2 = (i >> 3) & 63, kt = (i >> 9) & 1, nt = i >> 10;
            int k = kt * 32 + (l2 >> 4) * 8 + j, n = nt * 16 + (l2 & 15);
            W1b[i] = f2bf(W1[k * 128 + n]);
        }
    } else if (b == 1) {
        for (int i = t; i < 4096; i += 1024) {           // W2: 2 nt x 4 kt
            int j = i & 7, l2 = (i >> 3) & 63, kt = (i >> 9) & 3, nt = i >> 11;
            int k = kt * 32 + (l2 >> 4) * 8 + j, n = nt * 16 + (l2 & 15);
            W2b[i] = f2bf(W2[k * 32 + n]);
        }
    }
}

// ---- level-1 exclusive scan: within-digit prefixes + per-digit totals (bsum) ----
__global__ void k_scan_a(const int* __restrict__ cnt, int* __restrict__ excl,
                         int* __restrict__ bsum, int n) {
    __shared__ int s[256];
    int idx = blockIdx.x * 256 + threadIdx.x;
    int v = (idx < n) ? cnt[idx] : 0;
    s[threadIdx.x] = v;
    __syncthreads();
    for (int off = 1; off < 256; off <<= 1) {
        int t = (threadIdx.x >= off) ? s[threadIdx.x - off] : 0;
        __syncthreads();
        s[threadIdx.x] += t;
        __syncthreads();
    }
    if (idx < n) excl[idx] = s[threadIdx.x] - v;
    if (threadIdx.x == 255) bsum[blockIdx.x] = s[255];
}

// ---- partition: digit-level offsets computed in-LDS from bsum (256-val scans) ----
__global__ __launch_bounds__(1024) void k_part(const int* __restrict__ row,
                                               const int* __restrict__ col, int E, int chunk,
                                               const int* __restrict__ excl,
                                               const int* __restrict__ bsum,
                                               unsigned* __restrict__ cbuf,
                                               unsigned short* __restrict__ rbuf) {
    __shared__ int offc[256], offr[256], s[256];
    int t = threadIdx.x, b = blockIdx.x;
    // col digit scan
    if (t < 256) s[t] = bsum[t];
    __syncthreads();
    for (int off = 1; off < 256; off <<= 1) {
        int u = (t < 256 && t >= off) ? s[t - off] : 0;
        __syncthreads();
        if (t < 256) s[t] += u;
        __syncthreads();
    }
    if (t < 256) offc[t] = s[t] - bsum[t] + excl[t * 256 + b];
    __syncthreads();
    // row digit scan
    if (t < 256) s[t] = bsum[256 + t];
    __syncthreads();
    for (int off = 1; off < 256; off <<= 1) {
        int u = (t < 256 && t >= off) ? s[t - off] : 0;
        __syncthreads();
        if (t < 256) s[t] += u;
        __syncthreads();
    }
    if (t < 256) offr[t] = s[t] - bsum[256 + t] + excl[65536 + t * 256 + b];
    __syncthreads();
    int lo = b * chunk, hi = min(E, lo + chunk);
    for (int i = lo + t; i < hi; i += 1024) {
        int r = row[i], c = col[i];
        int pc = atomicAdd(&offc[c >> 8], 1);
        cbuf[pc] = ((unsigned)c << 16) | (unsigned)r;
        int pr = atomicAdd(&offr[r >> 8], 1);
        rbuf[pr] = (unsigned short)r;
    }
}

// ---- merged per-bucket build: blocks [0,nbk) deg->dis->xt; [nbk,2nbk) CSR ----
__global__ __launch_bounds__(256) void k_build(const unsigned short* __restrict__ rbuf,
                                               const unsigned* __restrict__ cbuf,
                                               const int* __restrict__ bsum,
                                               const int* __restrict__ priv,
                                               const float* __restrict__ x, int N, int E, int nbk,
                                               float* __restrict__ dis,
                                               unsigned short* __restrict__ xt,
                                               int* __restrict__ cntC, int* __restrict__ colStart,
                                               unsigned short* __restrict__ eSrc) {
    __shared__ int s1[256], s2[256], s3[256];
    int t = threadIdx.x;
    if ((int)blockIdx.x < nbk) {
        // ---- deg -> dis -> bf16 xt ----
        int b = blockIdx.x;
        s1[t] = (t < b) ? bsum[256 + t] : 0;   // prefix of row-digit totals
        __syncthreads();
        for (int off = 128; off > 0; off >>= 1) {
            if (t < off) s1[t] += s1[t + off];
            __syncthreads();
        }
        int rs = s1[0];
        int re = rs + bsum[256 + b];
        __syncthreads();
        s1[t] = 0;
        __syncthreads();
        for (int i = rs + t; i < re; i += 256) atomicAdd(&s1[rbuf[i] & 255], 1);
        __syncthreads();
        int node = b * 256 + t;
        float dv = rsqrtf((float)(s1[t] + 1));       // +1 self loop
        if (node < N) {
            dis[node] = dv;
            s2[t] = __float_as_int(dv);
            s3[t] = priv[node];
        } else { s2[t] = 0; s3[t] = 0; }
        __syncthreads();
        int base = b * 256;
        for (int i = t; i < 256 * 16; i += 256) {     // 16 float4 per node
            int ln = i >> 4;
            int n2 = base + ln;
            if (n2 >= N) continue;
            float d2 = __int_as_float(s2[ln]);
            int p = s3[ln];
            float4 v = ((const float4*)x)[(size_t)n2 * 16 + (i & 15)];
            float4 tr;
            tr.x = p ? fmaf(C1, v.x, C0) : v.x;
            tr.y = p ? fmaf(C1, v.y, C0) : v.y;
            tr.z = p ? fmaf(C1, v.z, C0) : v.z;
            tr.w = p ? fmaf(C1, v.w, C0) : v.w;
            ushort4 o;
            o.x = f2bf(d2 * tr.x); o.y = f2bf(d2 * tr.y);
            o.z = f2bf(d2 * tr.z); o.w = f2bf(d2 * tr.w);
            ((ushort4*)xt)[(size_t)n2 * 16 + (i & 15)] = o;
        }
    } else {
        // ---- CSR: cntC/colStart + eSrc[pos] = row (u16) ----
        int b = blockIdx.x - nbk;
        s1[t] = (t < b) ? bsum[t] : 0;          // prefix of col-digit totals
        __syncthreads();
        for (int off = 128; off > 0; off >>= 1) {
            if (t < off) s1[t] += s1[t + off];
            __syncthreads();
        }
        int cs = s1[0];
        int ce = cs + bsum[b];
        __syncthreads();
        s1[t] = 0; s3[t] = 0;
        __syncthreads();
        for (int i = cs + t; i < ce; i += 256) atomicAdd(&s1[(cbuf[i] >> 16) & 255], 1);
        __syncthreads();
        int v = s1[t];
        s2[t] = v;
        __syncthreads();
        for (int off = 1; off < 256; off <<= 1) {
            int u = (t >= off) ? s2[t - off] : 0;
            __syncthreads();
            s2[t] += u;
            __syncthreads();
        }
        int excl = s2[t] - v;
        int c = b * 256 + t;
        if (c < N) { cntC[c] = v; colStart[c] = cs + excl; }
        __syncthreads();
        s2[t] = excl;
        __syncthreads();
        for (int i = cs + t; i < ce; i += 256) {
            unsigned e = cbuf[i];
            int d = (e >> 16) & 255;
            int pos = cs + s2[d] + atomicAdd(&s3[d], 1);
            eSrc[pos] = (unsigned short)(e & 0xFFFFu);
        }
    }
}

// conv1 by gather: agg1b[c] = bf16( dis_c * (xt_c + sum_r xt_r) ); wave per c, 8x unroll
__global__ __launch_bounds__(256) void k_gather1(const unsigned short* __restrict__ xt,
                                                 const unsigned short* __restrict__ eSrc,
                                                 const int* __restrict__ colStart,
                                                 const int* __restrict__ cntC,
                                                 const float* __restrict__ dis,
                                                 unsigned short* __restrict__ agg1b, int N) {
    int t = blockIdx.x * blockDim.x + threadIdx.x;
    int c = t >> 6, d = t & 63;
    if (c >= N) return;
    float s = bf2f(xt[(size_t)c * 64 + d]);   // self loop term
    int start = colStart[c], cnt = cntC[c];
    for (int base = 0; base < cnt; base += 64) {
        int m = min(cnt - base, 64);
        int ids = (d < m) ? (int)eSrc[start + base + d] : 0;
        int k = 0;
        for (; k + 8 <= m; k += 8) {
            int r0 = __shfl(ids, k),     r1 = __shfl(ids, k + 1);
            int r2 = __shfl(ids, k + 2), r3 = __shfl(ids, k + 3);
            int r4 = __shfl(ids, k + 4), r5 = __shfl(ids, k + 5);
            int r6 = __shfl(ids, k + 6), r7 = __shfl(ids, k + 7);
            float x0 = bf2f(xt[(size_t)r0 * 64 + d]);
            float x1 = bf2f(xt[(size_t)r1 * 64 + d]);
            float x2 = bf2f(xt[(size_t)r2 * 64 + d]);
            float x3 = bf2f(xt[(size_t)r3 * 64 + d]);
            float x4 = bf2f(xt[(size_t)r4 * 64 + d]);
            float x5 = bf2f(xt[(size_t)r5 * 64 + d]);
            float x6 = bf2f(xt[(size_t)r6 * 64 + d]);
            float x7 = bf2f(xt[(size_t)r7 * 64 + d]);
            s += x0; s += x1; s += x2; s += x3;
            s += x4; s += x5; s += x6; s += x7;
        }
        for (; k + 4 <= m; k += 4) {
            int r0 = __shfl(ids, k),     r1 = __shfl(ids, k + 1);
            int r2 = __shfl(ids, k + 2), r3 = __shfl(ids, k + 3);
            float x0 = bf2f(xt[(size_t)r0 * 64 + d]);
            float x1 = bf2f(xt[(size_t)r1 * 64 + d]);
            float x2 = bf2f(xt[(size_t)r2 * 64 + d]);
            float x3 = bf2f(xt[(size_t)r3 * 64 + d]);
            s += x0; s += x1; s += x2; s += x3;
        }
        for (; k < m; ++k) {
            int r = __shfl(ids, k);
            s += bf2f(xt[(size_t)r * 64 + d]);
        }
    }
    agg1b[(size_t)c * 64 + d] = f2bf(dis[c] * s);
}

// ---- MFMA MLP: hps = bf16(dis * (relu(A@W1+b1)@W2)); 64-node tile, 4 waves ----
// Wave w owns rows w*16..w*16+15: layer1 C-strip stays in-wave; LDS relayout C->A.
__global__ __launch_bounds__(256) void k_mlp_mfma(const unsigned short* __restrict__ agg1b,
                                                  const unsigned short* __restrict__ W1b,
                                                  const float* __restrict__ b1,
                                                  const unsigned short* __restrict__ W2b,
                                                  const float* __restrict__ dis,
                                                  unsigned short* __restrict__ hps, int N) {
    __shared__ unsigned short hidA[4][16 * 136];   // per-wave 16 x 128 (+8 pad), 17 KB
    const int t = threadIdx.x;
    const int w = t >> 6, l = t & 63;
    const int q = l >> 4, lm = l & 15;
    const int rowbase = blockIdx.x * 64 + w * 16;

    // A frags (layer1): A[m=lm][k = kt*32 + q*8 + j] -> 16B contiguous per lane
    bf16x8 a0, a1;
    {
        int node = rowbase + lm;
        if (node >= N) node = N - 1;
        const bf16x8* pa = (const bf16x8*)(agg1b + (size_t)node * 64);
        a0 = pa[q];
        a1 = pa[4 + q];
    }
    float dvals[4];
    #pragma unroll
    for (int r = 0; r < 4; ++r) {
        int node = rowbase + q * 4 + r;
        dvals[r] = (node < N) ? dis[node] : 0.f;
    }

    const bf16x8* w1f = (const bf16x8*)W1b;
    #pragma unroll
    for (int nt = 0; nt < 8; ++nt) {
        float bv = b1[nt * 16 + lm];               // C col = lm for all 4 regs
        f32x4 acc = {bv, bv, bv, bv};
        acc = __builtin_amdgcn_mfma_f32_16x16x32_bf16(a0, w1f[(nt * 2 + 0) * 64 + l], acc, 0, 0, 0);
        acc = __builtin_amdgcn_mfma_f32_16x16x32_bf16(a1, w1f[(nt * 2 + 1) * 64 + l], acc, 0, 0, 0);
        #pragma unroll
        for (int r = 0; r < 4; ++r)                // row=q*4+r, col=nt*16+lm
            hidA[w][(q * 4 + r) * 136 + nt * 16 + lm] = f2bf(fmaxf(acc[r], 0.f));
    }
    __syncthreads();

    // layer2 A frags from hidA: A[m=lm][k=kt*32+q*8+j]; row stride 272B (16B-aligned)
    bf16x8 ha[4];
    #pragma unroll
    for (int kt = 0; kt < 4; ++kt)
        ha[kt] = *(const bf16x8*)&hidA[w][lm * 136 + kt * 32 + q * 8];

    const bf16x8* w2f = (const bf16x8*)W2b;
    #pragma unroll
    for (int nt = 0; nt < 2; ++nt) {
        f32x4 acc = {0.f, 0.f, 0.f, 0.f};
        #pragma unroll
        for (int kt = 0; kt < 4; ++kt)
            acc = __builtin_amdgcn_mfma_f32_16x16x32_bf16(ha[kt], w2f[(nt * 4 + kt) * 64 + l], acc, 0, 0, 0);
        #pragma unroll
        for (int r = 0; r < 4; ++r) {
            int node = rowbase + q * 4 + r;
            if (node < N)
                hps[(size_t)node * 32 + nt * 16 + lm] = f2bf(acc[r] * dvals[r]);
        }
    }
}

// conv2 by gather: out[c] = b2 - dis_c * (hps_c + sum_r hps_r); 32 lanes per c, 8x unroll
__global__ __launch_bounds__(256) void k_gather2(const unsigned short* __restrict__ hps,
                                                 const unsigned short* __restrict__ eSrc,
                                                 const int* __restrict__ colStart,
                                                 const int* __restrict__ cntC,
                                                 const float* __restrict__ dis,
                                                 const float* __restrict__ b2,
                                                 float* __restrict__ out, int N) {
    int t = blockIdx.x * blockDim.x + threadIdx.x;
    int c = t >> 5, j = t & 31;
    if (c >= N) return;
    float s = bf2f(hps[(size_t)c * 32 + j]);   // self loop
    int start = colStart[c], cnt = cntC[c];
    for (int base = 0; base < cnt; base += 32) {
        int m = min(cnt - base, 32);
        int ids = (j < m) ? (int)eSrc[start + base + j] : 0;
        int k = 0;
        for (; k + 8 <= m; k += 8) {
            int r0 = __shfl(ids, k, 32),     r1 = __shfl(ids, k + 1, 32);
            int r2 = __shfl(ids, k + 2, 32), r3 = __shfl(ids, k + 3, 32);
            int r4 = __shfl(ids, k + 4, 32), r5 = __shfl(ids, k + 5, 32);
            int r6 = __shfl(ids, k + 6, 32), r7 = __shfl(ids, k + 7, 32);
            float h0 = bf2f(hps[(size_t)r0 * 32 + j]);
            float h1 = bf2f(hps[(size_t)r1 * 32 + j]);
            float h2 = bf2f(hps[(size_t)r2 * 32 + j]);
            float h3 = bf2f(hps[(size_t)r3 * 32 + j]);
            float h4 = bf2f(hps[(size_t)r4 * 32 + j]);
            float h5 = bf2f(hps[(size_t)r5 * 32 + j]);
            float h6 = bf2f(hps[(size_t)r6 * 32 + j]);
            float h7 = bf2f(hps[(size_t)r7 * 32 + j]);
            s += h0; s += h1; s += h2; s += h3;
            s += h4; s += h5; s += h6; s += h7;
        }
        for (; k + 4 <= m; k += 4) {
            int r0 = __shfl(ids, k, 32),     r1 = __shfl(ids, k + 1, 32);
            int r2 = __shfl(ids, k + 2, 32), r3 = __shfl(ids, k + 3, 32);
            float h0 = bf2f(hps[(size_t)r0 * 32 + j]);
            float h1 = bf2f(hps[(size_t)r1 * 32 + j]);
            float h2 = bf2f(hps[(size_t)r2 * 32 + j]);
            float h3 = bf2f(hps[(size_t)r3 * 32 + j]);
            s += h0; s += h1; s += h2; s += h3;
        }
        for (; k < m; ++k) {
            int r = __shfl(ids, k, 32);
            s += bf2f(hps[(size_t)r * 32 + j]);
        }
    }
    out[(size_t)c * 32 + j] = b2[j] - dis[c] * s;
}

extern "C" void kernel_launch(void* const* d_in, const int* in_sizes, int n_in,
                              void* d_out, int out_size, void* d_ws, size_t ws_size,
                              hipStream_t stream) {
    const float* x    = (const float*)d_in[0];
    const int*   ei   = (const int*)d_in[1];
    const int*   priv = (const int*)d_in[2];
    const float* W1   = (const float*)d_in[3];
    const float* b1   = (const float*)d_in[4];
    const float* W2   = (const float*)d_in[5];
    const float* b2   = (const float*)d_in[6];
    float* out = (float*)d_out;

    const int N = in_sizes[2];
    const int E = in_sizes[1] / 2;
    const int* row = ei;
    const int* col = ei + E;

    char* ws = (char*)d_ws;
    size_t off = 0;
    auto take = [&](size_t bytes) { char* p = ws + off; off = (off + bytes + 255) & ~(size_t)255; return p; };
    int*            hist     = (int*)           take((size_t)131072 * 4);
    int*            excl     = (int*)           take((size_t)131072 * 4);
    int*            bsum     = (int*)           take(512 * 4);
    unsigned short* W1b      = (unsigned short*)take((size_t)8192 * 2);
    unsigned short* W2b      = (unsigned short*)take((size_t)4096 * 2);
    unsigned*       cbuf     = (unsigned*)      take((size_t)E * 4);
    unsigned short* rbuf     = (unsigned short*)take((size_t)E * 2);
    float*          dis      = (float*)         take((size_t)N * 4);
    int*            cntC     = (int*)           take((size_t)N * 4);
    int*            colStart = (int*)           take((size_t)N * 4);
    unsigned short* eSrc     = (unsigned short*)take((size_t)E * 2);
    unsigned short* xt       = (unsigned short*)take((size_t)N * 64 * 2);
    unsigned short* agg1b    = (unsigned short*)take((size_t)N * 64 * 2);
    unsigned short* hps      = (unsigned short*)take((size_t)N * 32 * 2);
    (void)ws_size;

    const int chunk = (E + 255) / 256;
    const int nbk = (N + 255) / 256;     // node buckets (196 < 255)

    k_hist2   <<<256, 1024, 0, stream>>>(row, col, E, chunk, hist, W1, W2, W1b, W2b);
    k_scan_a  <<<512, 256, 0, stream>>>(hist, excl, bsum, 131072);
    k_part    <<<256, 1024, 0, stream>>>(row, col, E, chunk, excl, bsum, cbuf, rbuf);
    k_build   <<<2 * nbk, 256, 0, stream>>>(rbuf, cbuf, bsum, priv, x, N, E, nbk,
                                            dis, xt, cntC, colStart, eSrc);
    k_gather1 <<<((size_t)N * 64 + 255) / 256, 256, 0, stream>>>(xt, eSrc, colStart, cntC, dis, agg1b, N);
    k_mlp_mfma<<<(N + 63) / 64, 256, 0, stream>>>(agg1b, W1b, b1, W2b, dis, hps, N);
    k_gather2 <<<((size_t)N * 32 + 255) / 256, 256, 0, stream>>>(hps, eSrc, colStart, cntC, dis, b2, out, N);
}